// Round 1
// baseline (6228.368 us; speedup 1.0000x reference)
//
#include <hip/hip_runtime.h>
#include <stdint.h>

#define N_ROWS 65536
#define K_CODES 8192
#define D_DIM 512
#define EPS_NORM 1e-12f

// ---------------------------------------------------------------------------
// Kernel 1: row L2-normalization (F.normalize semantics: x / max(||x||, eps)).
// One wave (64 lanes) per row; 512 floats = 128 float4 = 2 float4/lane.
// Also emits sum(xn*xn) computed AFTER rounding, matching the reference.
// ---------------------------------------------------------------------------
__global__ __launch_bounds__(64) void normalize_rows_kernel(
    const float* __restrict__ x, float* __restrict__ xn,
    float* __restrict__ n2out) {
  const int row = blockIdx.x;
  const int lane = threadIdx.x;
  const float4* xr = (const float4*)(x + (size_t)row * D_DIM);
  float4 v0 = xr[lane];
  float4 v1 = xr[lane + 64];

  float ss = v0.x * v0.x + v0.y * v0.y + v0.z * v0.z + v0.w * v0.w
           + v1.x * v1.x + v1.y * v1.y + v1.z * v1.z + v1.w * v1.w;
#pragma unroll
  for (int s = 32; s > 0; s >>= 1) ss += __shfl_xor(ss, s, 64);

  const float m = fmaxf(sqrtf(ss), EPS_NORM);

  float4 o0, o1;
  o0.x = v0.x / m; o0.y = v0.y / m; o0.z = v0.z / m; o0.w = v0.w / m;
  o1.x = v1.x / m; o1.y = v1.y / m; o1.z = v1.z / m; o1.w = v1.w / m;

  float s2 = o0.x * o0.x + o0.y * o0.y + o0.z * o0.z + o0.w * o0.w
           + o1.x * o1.x + o1.y * o1.y + o1.z * o1.z + o1.w * o1.w;
#pragma unroll
  for (int s = 32; s > 0; s >>= 1) s2 += __shfl_xor(s2, s, 64);

  float4* xo = (float4*)(xn + (size_t)row * D_DIM);
  xo[lane] = o0;
  xo[lane + 64] = o1;
  if (lane == 0) n2out[row] = s2;
}

// ---------------------------------------------------------------------------
// Kernel 2: init argmin keys to +inf
// ---------------------------------------------------------------------------
__global__ void init_keys_kernel(unsigned long long* __restrict__ keys) {
  int i = blockIdx.x * blockDim.x + threadIdx.x;
  keys[i] = 0xFFFFFFFFFFFFFFFFull;
}

// ---------------------------------------------------------------------------
// Kernel 3: fp32 tiled GEMM (zn @ cb^T) fused with running argmin of
//   d = (znorm2 - 2*dot) + cnorm2   (reference's evaluation order)
// Tile: BM=128 x BN=128, BK=16. 256 threads, 8x8 micro-tile per thread.
// Argmin key = (orderable_float_bits(d) << 32) | col  -> 64-bit atomicMin
// gives exact lowest-index tie-break, order-independent across blocks.
// ---------------------------------------------------------------------------
#define BM 128
#define BN 128
#define BK 16
#define LDT 132  // padded LDS row stride (floats); 132*4=528 B keeps 16B align

__global__ __launch_bounds__(256) void gemm_argmin_kernel(
    const float* __restrict__ zn, const float* __restrict__ cb,
    const float* __restrict__ znorm2, const float* __restrict__ cnorm2,
    unsigned long long* __restrict__ keys) {
  __shared__ float As[BK * LDT];
  __shared__ float Bs[BK * LDT];

  const int m0 = blockIdx.y * BM;
  const int n0 = blockIdx.x * BN;
  const int tid = (int)threadIdx.x;
  const int tx = tid & 15;   // col group
  const int ty = tid >> 4;   // row group
  const int lrow = tid >> 2;       // 0..63 (staging row)
  const int lc4 = (tid & 3) * 4;   // 0,4,8,12 (staging d offset)

  float acc[8][8];
#pragma unroll
  for (int i = 0; i < 8; i++)
#pragma unroll
    for (int j = 0; j < 8; j++) acc[i][j] = 0.0f;

  const float* aptr0 = zn + (size_t)(m0 + lrow) * D_DIM + lc4;
  const float* aptr1 = zn + (size_t)(m0 + lrow + 64) * D_DIM + lc4;
  const float* bptr0 = cb + (size_t)(n0 + lrow) * D_DIM + lc4;
  const float* bptr1 = cb + (size_t)(n0 + lrow + 64) * D_DIM + lc4;

  for (int d0 = 0; d0 < D_DIM; d0 += BK) {
    float4 a0 = *(const float4*)(aptr0 + d0);
    float4 a1 = *(const float4*)(aptr1 + d0);
    float4 b0 = *(const float4*)(bptr0 + d0);
    float4 b1 = *(const float4*)(bptr1 + d0);
    __syncthreads();  // previous iter's LDS reads done before overwrite
#pragma unroll
    for (int i = 0; i < 4; i++) {
      As[(lc4 + i) * LDT + lrow]      = (&a0.x)[i];
      As[(lc4 + i) * LDT + lrow + 64] = (&a1.x)[i];
      Bs[(lc4 + i) * LDT + lrow]      = (&b0.x)[i];
      Bs[(lc4 + i) * LDT + lrow + 64] = (&b1.x)[i];
    }
    __syncthreads();
#pragma unroll
    for (int d = 0; d < BK; d++) {
      float ar[8], br[8];
      *(float4*)&ar[0] = *(const float4*)&As[d * LDT + ty * 4];
      *(float4*)&ar[4] = *(const float4*)&As[d * LDT + 64 + ty * 4];
      *(float4*)&br[0] = *(const float4*)&Bs[d * LDT + tx * 4];
      *(float4*)&br[4] = *(const float4*)&Bs[d * LDT + 64 + tx * 4];
#pragma unroll
      for (int i = 0; i < 8; i++)
#pragma unroll
        for (int j = 0; j < 8; j++)
          acc[i][j] = fmaf(ar[i], br[j], acc[i][j]);
    }
  }

  // ---- epilogue: distances + per-row argmin ----
  float cn2[8];
#pragma unroll
  for (int j = 0; j < 8; j++) {
    int c = (j < 4) ? (tx * 4 + j) : (64 + tx * 4 + j - 4);
    cn2[j] = cnorm2[n0 + c];
  }
#pragma unroll
  for (int i = 0; i < 8; i++) {
    int r = (i < 4) ? (ty * 4 + i) : (64 + ty * 4 + i - 4);
    float rn2 = znorm2[m0 + r];
    unsigned long long best = 0xFFFFFFFFFFFFFFFFull;
#pragma unroll
    for (int j = 0; j < 8; j++) {
      int c = (j < 4) ? (tx * 4 + j) : (64 + tx * 4 + j - 4);
      // match numpy rounding order; block fp-contraction
      float t = __fmul_rn(2.0f, acc[i][j]);
      float u = __fsub_rn(rn2, t);
      float dist = __fadd_rn(u, cn2[j]);
      unsigned ub = __float_as_uint(dist);
      ub = (ub & 0x80000000u) ? ~ub : (ub | 0x80000000u);  // total order map
      unsigned long long key =
          ((unsigned long long)ub << 32) | (unsigned)(n0 + c);
      best = key < best ? key : best;
    }
    // reduce across the 16 threads (same ty) sharing these rows
#pragma unroll
    for (int s = 8; s > 0; s >>= 1) {
      unsigned lo = (unsigned)(best & 0xFFFFFFFFull);
      unsigned hi = (unsigned)(best >> 32);
      unsigned olo = (unsigned)__shfl_xor((int)lo, s, 64);
      unsigned ohi = (unsigned)__shfl_xor((int)hi, s, 64);
      unsigned long long o = ((unsigned long long)ohi << 32) | olo;
      best = o < best ? o : best;
    }
    if (tx == 0) atomicMin(keys + (m0 + r), best);
  }
}

// ---------------------------------------------------------------------------
// Kernel 4: gather code, project, write outputs. One wave per row.
// z_proj = (zn . cb[idx]) * cb[idx];  idx written as float after z_proj block.
// ---------------------------------------------------------------------------
__global__ __launch_bounds__(64) void finalize_kernel(
    const float* __restrict__ zn, const float* __restrict__ cb,
    const unsigned long long* __restrict__ keys, float* __restrict__ out) {
  const int row = blockIdx.x;
  const int lane = threadIdx.x;
  const unsigned idx = (unsigned)(keys[row] & 0xFFFFFFFFull);

  const float4* zr = (const float4*)(zn + (size_t)row * D_DIM);
  const float4* qr = (const float4*)(cb + (size_t)idx * D_DIM);
  float4 z0 = zr[lane], z1 = zr[lane + 64];
  float4 q0 = qr[lane], q1 = qr[lane + 64];

  float p = z0.x * q0.x + z0.y * q0.y + z0.z * q0.z + z0.w * q0.w
          + z1.x * q1.x + z1.y * q1.y + z1.z * q1.z + z1.w * q1.w;
#pragma unroll
  for (int s = 32; s > 0; s >>= 1) p += __shfl_xor(p, s, 64);

  float4 o0, o1;
  o0.x = p * q0.x; o0.y = p * q0.y; o0.z = p * q0.z; o0.w = p * q0.w;
  o1.x = p * q1.x; o1.y = p * q1.y; o1.z = p * q1.z; o1.w = p * q1.w;

  float4* orow = (float4*)(out + (size_t)row * D_DIM);
  orow[lane] = o0;
  orow[lane + 64] = o1;
  if (lane == 0) out[(size_t)N_ROWS * D_DIM + row] = (float)idx;
}

// ---------------------------------------------------------------------------
extern "C" void kernel_launch(void* const* d_in, const int* in_sizes, int n_in,
                              void* d_out, int out_size, void* d_ws,
                              size_t ws_size, hipStream_t stream) {
  const float* z = (const float*)d_in[0];
  const float* emb = (const float*)d_in[1];
  float* out = (float*)d_out;

  // workspace layout (floats): zn[N*D] | cb[K*D] | znorm2[N] | cnorm2[K] | keys[N] (u64)
  float* zn = (float*)d_ws;
  float* cb = zn + (size_t)N_ROWS * D_DIM;
  float* znorm2 = cb + (size_t)K_CODES * D_DIM;
  float* cnorm2 = znorm2 + N_ROWS;
  unsigned long long* keys = (unsigned long long*)(cnorm2 + K_CODES);

  normalize_rows_kernel<<<K_CODES, 64, 0, stream>>>(emb, cb, cnorm2);
  normalize_rows_kernel<<<N_ROWS, 64, 0, stream>>>(z, zn, znorm2);
  init_keys_kernel<<<N_ROWS / 256, 256, 0, stream>>>(keys);

  dim3 grid(K_CODES / BN, N_ROWS / BM);
  gemm_argmin_kernel<<<grid, 256, 0, stream>>>(zn, cb, znorm2, cnorm2, keys);

  finalize_kernel<<<N_ROWS, 64, 0, stream>>>(zn, cb, keys, out);
}

// Round 2
// 1996.972 us; speedup vs baseline: 3.1189x; 3.1189x over previous
//
#include <hip/hip_runtime.h>
#include <stdint.h>

#define N_ROWS 65536
#define K_CODES 8192
#define D_DIM 512
#define EPS_NORM 1e-12f
#define NB 64            // number of 128-wide column blocks
#define MARGIN 2.0e-3f   // >= 2x hard bound on fp16 dot rounding error (9.8e-4)

typedef _Float16 f16x8 __attribute__((ext_vector_type(8)));
typedef _Float16 f16x4 __attribute__((ext_vector_type(4)));
typedef float f32x4 __attribute__((ext_vector_type(4)));
typedef unsigned long long u64;

__device__ __forceinline__ unsigned orderf(float f) {
  unsigned u = __float_as_uint(f);
  return (u & 0x80000000u) ? ~u : (u | 0x80000000u);
}
__device__ __forceinline__ float unorderf(unsigned ub) {
  unsigned u = (ub & 0x80000000u) ? (ub & 0x7FFFFFFFu) : ~ub;
  return __uint_as_float(u);
}
__device__ __forceinline__ unsigned umin32(unsigned a, unsigned b) { return a < b ? a : b; }
__device__ __forceinline__ u64 umin64(u64 a, u64 b) { return a < b ? a : b; }
__device__ __forceinline__ u64 shfl_xor_u64(u64 v, int m) {
  unsigned lo = (unsigned)__shfl_xor((int)(unsigned)(v & 0xFFFFFFFFull), m, 64);
  unsigned hi = (unsigned)__shfl_xor((int)(unsigned)(v >> 32), m, 64);
  return ((u64)hi << 32) | (u64)lo;
}
__device__ __forceinline__ void async_copy16(void* lds, const void* g) {
  __builtin_amdgcn_global_load_lds(
      (const __attribute__((address_space(1))) void*)g,
      (__attribute__((address_space(3))) void*)lds, 16, 0, 0);
}

// ---------------------------------------------------------------------------
// prep: L2-normalize rows (exact F.normalize semantics: x / max(||x||,eps)),
// emit fp16 copy for MFMA screening. z-path also stores norm + post-round
// sum-of-squares; cb-path stores fp32 normalized codebook + cnorm2.
// ---------------------------------------------------------------------------
__global__ __launch_bounds__(64) void prep_z_kernel(
    const float* __restrict__ z, _Float16* __restrict__ znh,
    float* __restrict__ znorm, float* __restrict__ znorm2) {
  const int row = blockIdx.x;
  const int lane = threadIdx.x;
  const float4* xr = (const float4*)(z + (size_t)row * D_DIM);
  float4 v0 = xr[lane];
  float4 v1 = xr[lane + 64];
  float ss = v0.x * v0.x + v0.y * v0.y + v0.z * v0.z + v0.w * v0.w
           + v1.x * v1.x + v1.y * v1.y + v1.z * v1.z + v1.w * v1.w;
#pragma unroll
  for (int s = 32; s > 0; s >>= 1) ss += __shfl_xor(ss, s, 64);
  const float m = fmaxf(sqrtf(ss), EPS_NORM);
  float4 o0, o1;
  o0.x = v0.x / m; o0.y = v0.y / m; o0.z = v0.z / m; o0.w = v0.w / m;
  o1.x = v1.x / m; o1.y = v1.y / m; o1.z = v1.z / m; o1.w = v1.w / m;
  float s2 = o0.x * o0.x + o0.y * o0.y + o0.z * o0.z + o0.w * o0.w
           + o1.x * o1.x + o1.y * o1.y + o1.z * o1.z + o1.w * o1.w;
#pragma unroll
  for (int s = 32; s > 0; s >>= 1) s2 += __shfl_xor(s2, s, 64);
  f16x4 h0, h1;
  h0[0] = (_Float16)o0.x; h0[1] = (_Float16)o0.y; h0[2] = (_Float16)o0.z; h0[3] = (_Float16)o0.w;
  h1[0] = (_Float16)o1.x; h1[1] = (_Float16)o1.y; h1[2] = (_Float16)o1.z; h1[3] = (_Float16)o1.w;
  *(f16x4*)(znh + (size_t)row * D_DIM + lane * 4) = h0;
  *(f16x4*)(znh + (size_t)row * D_DIM + 256 + lane * 4) = h1;
  if (lane == 0) { znorm[row] = m; znorm2[row] = s2; }
}

__global__ __launch_bounds__(64) void prep_cb_kernel(
    const float* __restrict__ emb, float* __restrict__ cb32,
    _Float16* __restrict__ cbh, float* __restrict__ cnorm2) {
  const int row = blockIdx.x;
  const int lane = threadIdx.x;
  const float4* xr = (const float4*)(emb + (size_t)row * D_DIM);
  float4 v0 = xr[lane];
  float4 v1 = xr[lane + 64];
  float ss = v0.x * v0.x + v0.y * v0.y + v0.z * v0.z + v0.w * v0.w
           + v1.x * v1.x + v1.y * v1.y + v1.z * v1.z + v1.w * v1.w;
#pragma unroll
  for (int s = 32; s > 0; s >>= 1) ss += __shfl_xor(ss, s, 64);
  const float m = fmaxf(sqrtf(ss), EPS_NORM);
  float4 o0, o1;
  o0.x = v0.x / m; o0.y = v0.y / m; o0.z = v0.z / m; o0.w = v0.w / m;
  o1.x = v1.x / m; o1.y = v1.y / m; o1.z = v1.z / m; o1.w = v1.w / m;
  float s2 = o0.x * o0.x + o0.y * o0.y + o0.z * o0.z + o0.w * o0.w
           + o1.x * o1.x + o1.y * o1.y + o1.z * o1.z + o1.w * o1.w;
#pragma unroll
  for (int s = 32; s > 0; s >>= 1) s2 += __shfl_xor(s2, s, 64);
  float4* co = (float4*)(cb32 + (size_t)row * D_DIM);
  co[lane] = o0;
  co[lane + 64] = o1;
  f16x4 h0, h1;
  h0[0] = (_Float16)o0.x; h0[1] = (_Float16)o0.y; h0[2] = (_Float16)o0.z; h0[3] = (_Float16)o0.w;
  h1[0] = (_Float16)o1.x; h1[1] = (_Float16)o1.y; h1[2] = (_Float16)o1.z; h1[3] = (_Float16)o1.w;
  *(f16x4*)(cbh + (size_t)row * D_DIM + lane * 4) = h0;
  *(f16x4*)(cbh + (size_t)row * D_DIM + 256 + lane * 4) = h1;
  if (lane == 0) cnorm2[row] = s2;
}

__global__ void zero_count_kernel(unsigned* __restrict__ count) {
  if (threadIdx.x == 0) count[0] = 0;
}

// ---------------------------------------------------------------------------
// Screening GEMM: S = znh . cbh^T via mfma_f32_16x16x32_f16.
// Block = 128x128 tile, 256 threads = 4 waves; wave w owns rows [w*32, w*32+32)
// x all 128 cols (2 m-tiles x 8 n-tiles of 16x16) -> no cross-wave merge.
// Staging: global_load_lds width=16, LDS layout [row][k] with 64 B rows so the
// wave-uniform-base + lane*16 DMA pattern lands exactly (no padding!).
// Epilogue: per-(row, block) top-1 key = (ordered_bits(-dot)<<32 | col) and
// top-2 value, written to K1/K2.
// ---------------------------------------------------------------------------
__global__ __launch_bounds__(256) void screen_gemm_kernel(
    const _Float16* __restrict__ znh, const _Float16* __restrict__ cbh,
    u64* __restrict__ K1, unsigned* __restrict__ K2) {
  __shared__ _Float16 Ash[128 * 32];
  __shared__ _Float16 Bsh[128 * 32];
  const int tid = (int)threadIdx.x;
  const int lane = tid & 63;
  const int w = tid >> 6;
  const int m0 = blockIdx.y * 128;
  const int n0 = blockIdx.x * 128;

  f32x4 acc[2][8];
  const f32x4 z4 = {0.0f, 0.0f, 0.0f, 0.0f};
#pragma unroll
  for (int i = 0; i < 2; i++)
#pragma unroll
    for (int j = 0; j < 8; j++) acc[i][j] = z4;

  // staging: wave w fills LDS byte ranges [w*2048, (w+1)*2048) in each array,
  // i.e. rows w*32 .. w*32+31 (64 B per row). lane l -> base + l*16.
  const int srow = lane >> 2;            // 0..15
  const int kc = (lane & 3) * 8;         // f16 offset within row: 0,8,16,24
  const _Float16* gA0 = znh + (size_t)(m0 + w * 32 + srow) * D_DIM + kc;
  const _Float16* gA1 = znh + (size_t)(m0 + w * 32 + 16 + srow) * D_DIM + kc;
  const _Float16* gB0 = cbh + (size_t)(n0 + w * 32 + srow) * D_DIM + kc;
  const _Float16* gB1 = cbh + (size_t)(n0 + w * 32 + 16 + srow) * D_DIM + kc;
  _Float16* lA0 = Ash + w * 1024;
  _Float16* lA1 = Ash + w * 1024 + 512;
  _Float16* lB0 = Bsh + w * 1024;
  _Float16* lB1 = Bsh + w * 1024 + 512;

  const int q = lane >> 4;               // k-chunk 0..3
  const int c15 = lane & 15;
  const _Float16* aRd = Ash + (w * 32 + c15) * 32 + q * 8;
  const _Float16* bRd = Bsh + c15 * 32 + q * 8;

  for (int d0 = 0; d0 < D_DIM; d0 += 32) {
    __syncthreads();  // prior iter's LDS reads complete before overwrite
    async_copy16(lA0, gA0 + d0);
    async_copy16(lA1, gA1 + d0);
    async_copy16(lB0, gB0 + d0);
    async_copy16(lB1, gB1 + d0);
    __syncthreads();  // vmcnt(0)-drained barrier: tiles visible
    f16x8 a0 = *(const f16x8*)(aRd);
    f16x8 a1 = *(const f16x8*)(aRd + 16 * 32);
    f16x8 bf[8];
#pragma unroll
    for (int nt = 0; nt < 8; nt++) bf[nt] = *(const f16x8*)(bRd + nt * 16 * 32);
#pragma unroll
    for (int nt = 0; nt < 8; nt++) {
      acc[0][nt] = __builtin_amdgcn_mfma_f32_16x16x32_f16(a0, bf[nt], acc[0][nt], 0, 0, 0);
      acc[1][nt] = __builtin_amdgcn_mfma_f32_16x16x32_f16(a1, bf[nt], acc[1][nt], 0, 0, 0);
    }
  }

  // epilogue: per row, top-2 of s = -dot over this block's 128 cols.
  // C/D layout: col = lane&15, row = (lane>>4)*4 + reg.
#pragma unroll
  for (int mt = 0; mt < 2; mt++) {
#pragma unroll
    for (int r = 0; r < 4; r++) {
      u64 key1 = ~0ull;
      unsigned b2 = 0xFFFFFFFFu;
#pragma unroll
      for (int nt = 0; nt < 8; nt++) {
        unsigned ub = orderf(-acc[mt][nt][r]);
        unsigned col = (unsigned)(n0 + nt * 16 + c15);
        u64 k = ((u64)ub << 32) | (u64)col;
        unsigned v1 = (unsigned)(key1 >> 32);
        if (k < key1) { b2 = umin32(b2, v1); key1 = k; }
        else          { b2 = umin32(b2, ub); }
      }
#pragma unroll
      for (int s = 1; s <= 8; s <<= 1) {
        u64 ok = shfl_xor_u64(key1, s);
        unsigned ob2 = (unsigned)__shfl_xor((int)b2, s, 64);
        unsigned ov = (unsigned)(ok >> 32);
        unsigned v1 = (unsigned)(key1 >> 32);
        unsigned lose = (ok < key1) ? v1 : ov;
        b2 = umin32(umin32(b2, ob2), lose);
        key1 = umin64(key1, ok);
      }
      if (c15 == 0) {
        const int mrow = m0 + w * 32 + mt * 16 + q * 4 + r;
        K1[(size_t)mrow * NB + blockIdx.x] = key1;
        K2[(size_t)mrow * NB + blockIdx.x] = b2;
      }
    }
  }
}

// ---------------------------------------------------------------------------
// Certify: per row, global top-1 and runner-up over 64 block entries.
// Gap > MARGIN -> approx argmin is provably the fp32 argmin. Otherwise queue
// the row for fp32 rescoring. One wave per row, lane = block index.
// ---------------------------------------------------------------------------
__global__ __launch_bounds__(256) void certify_kernel(
    const u64* __restrict__ K1, const unsigned* __restrict__ K2,
    unsigned* __restrict__ idx_final, unsigned* __restrict__ list,
    unsigned* __restrict__ count) {
  const int row = blockIdx.x * 4 + (int)(threadIdx.x >> 6);
  const int b = (int)(threadIdx.x & 63);
  u64 k = K1[(size_t)row * NB + b];
  unsigned r2 = K2[(size_t)row * NB + b];
  u64 kmin = k;
#pragma unroll
  for (int s = 1; s <= 32; s <<= 1) kmin = umin64(kmin, shfl_xor_u64(kmin, s));
  unsigned cand = (k == kmin) ? r2 : (unsigned)(k >> 32);
#pragma unroll
  for (int s = 1; s <= 32; s <<= 1)
    cand = umin32(cand, (unsigned)__shfl_xor((int)cand, s, 64));
  if (b == 0) {
    idx_final[row] = (unsigned)(kmin & 0xFFFFFFFFull);
    float t1 = unorderf((unsigned)(kmin >> 32));
    float ru = unorderf(cand);
    if (ru - t1 <= MARGIN) {
      unsigned p = atomicAdd(count, 1u);
      list[p] = (unsigned)row;
    }
  }
}

// ---------------------------------------------------------------------------
// Rescore uncertain rows: exact fp32 distances (round-1 semantics) over all
// codes of candidate blocks (block top-1 within MARGIN of global top-1).
// One wave per row, grid-stride over the list.
// ---------------------------------------------------------------------------
__global__ __launch_bounds__(64) void rescore_kernel(
    const float* __restrict__ z, const float* __restrict__ cb32,
    const float* __restrict__ znorm, const float* __restrict__ znorm2,
    const float* __restrict__ cnorm2, const u64* __restrict__ K1,
    const unsigned* __restrict__ list, const unsigned* __restrict__ count,
    unsigned* __restrict__ idx_final) {
  __shared__ float znl[D_DIM];
  const int lane = (int)threadIdx.x;
  const unsigned n = count[0];
  for (unsigned i = blockIdx.x; i < n; i += gridDim.x) {
    const int row = (int)list[i];
    const float m = znorm[row];
    const float4* zr = (const float4*)(z + (size_t)row * D_DIM);
    float4 v0 = zr[lane], v1 = zr[lane + 64];
    __syncthreads();  // prior iteration done with znl
    float4 o0, o1;
    o0.x = v0.x / m; o0.y = v0.y / m; o0.z = v0.z / m; o0.w = v0.w / m;
    o1.x = v1.x / m; o1.y = v1.y / m; o1.z = v1.z / m; o1.w = v1.w / m;
    *(float4*)&znl[lane * 4] = o0;
    *(float4*)&znl[256 + lane * 4] = o1;
    u64 k = K1[(size_t)row * NB + lane];
    u64 kmin = k;
#pragma unroll
    for (int s = 1; s <= 32; s <<= 1) kmin = umin64(kmin, shfl_xor_u64(kmin, s));
    const float t1 = unorderf((unsigned)(kmin >> 32));
    const bool cf = unorderf((unsigned)(k >> 32)) <= t1 + MARGIN;
    u64 mask = __ballot(cf);
    __syncthreads();  // znl visible to all lanes
    const float zn2 = znorm2[row];
    u64 best = ~0ull;
    while (mask) {
      const int b = __builtin_ctzll(mask);
      mask &= mask - 1;
#pragma unroll
      for (int h = 0; h < 2; h++) {
        const int c = b * 128 + h * 64 + lane;
        const float4* cr = (const float4*)(cb32 + (size_t)c * D_DIM);
        float dot = 0.0f;
        for (int d = 0; d < 128; d++) {
          float4 bb = cr[d];
          float4 aa = *(const float4*)&znl[d * 4];
          dot = __fmaf_rn(aa.x, bb.x, dot);
          dot = __fmaf_rn(aa.y, bb.y, dot);
          dot = __fmaf_rn(aa.z, bb.z, dot);
          dot = __fmaf_rn(aa.w, bb.w, dot);
        }
        float dist = __fadd_rn(__fsub_rn(zn2, __fmul_rn(2.0f, dot)), cnorm2[c]);
        u64 key = ((u64)orderf(dist) << 32) | (u64)(unsigned)c;
        best = umin64(best, key);
      }
    }
#pragma unroll
    for (int s = 1; s <= 32; s <<= 1) best = umin64(best, shfl_xor_u64(best, s));
    if (lane == 0) idx_final[row] = (unsigned)(best & 0xFFFFFFFFull);
  }
}

// ---------------------------------------------------------------------------
// Finalize: gather code, project, write outputs. One wave per row.
// ---------------------------------------------------------------------------
__global__ __launch_bounds__(64) void finalize_kernel(
    const float* __restrict__ z, const float* __restrict__ cb32,
    const float* __restrict__ znorm, const unsigned* __restrict__ idx_final,
    float* __restrict__ out) {
  const int row = blockIdx.x;
  const int lane = (int)threadIdx.x;
  const float m = znorm[row];
  const unsigned idx = idx_final[row];
  const float4* zr = (const float4*)(z + (size_t)row * D_DIM);
  const float4* qr = (const float4*)(cb32 + (size_t)idx * D_DIM);
  float4 v0 = zr[lane], v1 = zr[lane + 64];
  float4 q0 = qr[lane], q1 = qr[lane + 64];
  float4 z0, z1;
  z0.x = v0.x / m; z0.y = v0.y / m; z0.z = v0.z / m; z0.w = v0.w / m;
  z1.x = v1.x / m; z1.y = v1.y / m; z1.z = v1.z / m; z1.w = v1.w / m;
  float p = z0.x * q0.x + z0.y * q0.y + z0.z * q0.z + z0.w * q0.w
          + z1.x * q1.x + z1.y * q1.y + z1.z * q1.z + z1.w * q1.w;
#pragma unroll
  for (int s = 32; s > 0; s >>= 1) p += __shfl_xor(p, s, 64);
  float4 o0, o1;
  o0.x = p * q0.x; o0.y = p * q0.y; o0.z = p * q0.z; o0.w = p * q0.w;
  o1.x = p * q1.x; o1.y = p * q1.y; o1.z = p * q1.z; o1.w = p * q1.w;
  float4* orow = (float4*)(out + (size_t)row * D_DIM);
  orow[lane] = o0;
  orow[lane + 64] = o1;
  if (lane == 0) out[(size_t)N_ROWS * D_DIM + row] = (float)idx;
}

// ---------------------------------------------------------------------------
extern "C" void kernel_launch(void* const* d_in, const int* in_sizes, int n_in,
                              void* d_out, int out_size, void* d_ws,
                              size_t ws_size, hipStream_t stream) {
  const float* z = (const float*)d_in[0];
  const float* emb = (const float*)d_in[1];
  float* out = (float*)d_out;

  // ws layout (all offsets 256B-aligned), total ~137.5 MB:
  u64* K1 = (u64*)d_ws;                                   // N*64*8  = 32 MB
  unsigned* K2 = (unsigned*)(K1 + (size_t)N_ROWS * NB);   // N*64*4  = 16 MB
  float* cb32 = (float*)(K2 + (size_t)N_ROWS * NB);       // K*D*4   = 16 MB
  float* znorm = cb32 + (size_t)K_CODES * D_DIM;          // N*4
  float* znorm2 = znorm + N_ROWS;                         // N*4
  float* cnorm2 = znorm2 + N_ROWS;                        // K*4
  unsigned* idx_final = (unsigned*)(cnorm2 + K_CODES);    // N*4
  unsigned* list = idx_final + N_ROWS;                    // N*4
  unsigned* count = list + N_ROWS;                        // 64*4 pad
  _Float16* znh = (_Float16*)(count + 64);                // N*D*2  = 64 MB
  _Float16* cbh = znh + (size_t)N_ROWS * D_DIM;           // K*D*2  =  8 MB

  prep_z_kernel<<<N_ROWS, 64, 0, stream>>>(z, znh, znorm, znorm2);
  prep_cb_kernel<<<K_CODES, 64, 0, stream>>>(emb, cb32, cbh, cnorm2);
  zero_count_kernel<<<1, 64, 0, stream>>>(count);

  dim3 grid(K_CODES / 128, N_ROWS / 128);
  screen_gemm_kernel<<<grid, 256, 0, stream>>>(znh, cbh, K1, K2);

  certify_kernel<<<N_ROWS / 4, 256, 0, stream>>>(K1, K2, idx_final, list, count);
  rescore_kernel<<<4096, 64, 0, stream>>>(z, cb32, znorm, znorm2, cnorm2, K1,
                                          list, count, idx_final);
  finalize_kernel<<<N_ROWS, 64, 0, stream>>>(z, cb32, znorm, idx_final, out);
}

// Round 3
// 1388.235 us; speedup vs baseline: 4.4865x; 1.4385x over previous
//
#include <hip/hip_runtime.h>
#include <stdint.h>

#define N_ROWS 65536
#define K_CODES 8192
#define D_DIM 512
#define EPS_NORM 1e-12f
#define NB 64            // number of 128-wide column blocks
#define MARGIN 2.5e-3f   // > 2x hard bound on fp16 dot error (2*1.01e-3)
#define CAP 16           // max per-row candidate codes on the light path

typedef _Float16 f16x8 __attribute__((ext_vector_type(8)));
typedef _Float16 f16x4 __attribute__((ext_vector_type(4)));
typedef float f32x4 __attribute__((ext_vector_type(4)));
typedef unsigned long long u64;

__device__ __forceinline__ unsigned orderf(float f) {
  unsigned u = __float_as_uint(f);
  return (u & 0x80000000u) ? ~u : (u | 0x80000000u);
}
__device__ __forceinline__ float unorderf(unsigned ub) {
  unsigned u = (ub & 0x80000000u) ? (ub & 0x7FFFFFFFu) : ~ub;
  return __uint_as_float(u);
}
__device__ __forceinline__ unsigned umin32(unsigned a, unsigned b) { return a < b ? a : b; }
__device__ __forceinline__ u64 umin64(u64 a, u64 b) { return a < b ? a : b; }
__device__ __forceinline__ u64 shfl_xor_u64(u64 v, int m) {
  unsigned lo = (unsigned)__shfl_xor((int)(unsigned)(v & 0xFFFFFFFFull), m, 64);
  unsigned hi = (unsigned)__shfl_xor((int)(unsigned)(v >> 32), m, 64);
  return ((u64)hi << 32) | (u64)lo;
}
__device__ __forceinline__ void async_copy16(void* lds, const void* g) {
  __builtin_amdgcn_global_load_lds(
      (const __attribute__((address_space(1))) void*)g,
      (__attribute__((address_space(3))) void*)lds, 16, 0, 0);
}

// ---------------------------------------------------------------------------
// prep: L2-normalize rows (F.normalize semantics), emit fp16 copy for MFMA.
// ---------------------------------------------------------------------------
__global__ __launch_bounds__(64) void prep_z_kernel(
    const float* __restrict__ z, _Float16* __restrict__ znh,
    float* __restrict__ znorm, float* __restrict__ znorm2) {
  const int row = blockIdx.x;
  const int lane = threadIdx.x;
  const float4* xr = (const float4*)(z + (size_t)row * D_DIM);
  float4 v0 = xr[lane];
  float4 v1 = xr[lane + 64];
  float ss = v0.x * v0.x + v0.y * v0.y + v0.z * v0.z + v0.w * v0.w
           + v1.x * v1.x + v1.y * v1.y + v1.z * v1.z + v1.w * v1.w;
#pragma unroll
  for (int s = 32; s > 0; s >>= 1) ss += __shfl_xor(ss, s, 64);
  const float m = fmaxf(sqrtf(ss), EPS_NORM);
  float4 o0, o1;
  o0.x = v0.x / m; o0.y = v0.y / m; o0.z = v0.z / m; o0.w = v0.w / m;
  o1.x = v1.x / m; o1.y = v1.y / m; o1.z = v1.z / m; o1.w = v1.w / m;
  float s2 = o0.x * o0.x + o0.y * o0.y + o0.z * o0.z + o0.w * o0.w
           + o1.x * o1.x + o1.y * o1.y + o1.z * o1.z + o1.w * o1.w;
#pragma unroll
  for (int s = 32; s > 0; s >>= 1) s2 += __shfl_xor(s2, s, 64);
  f16x4 h0, h1;
  h0[0] = (_Float16)o0.x; h0[1] = (_Float16)o0.y; h0[2] = (_Float16)o0.z; h0[3] = (_Float16)o0.w;
  h1[0] = (_Float16)o1.x; h1[1] = (_Float16)o1.y; h1[2] = (_Float16)o1.z; h1[3] = (_Float16)o1.w;
  *(f16x4*)(znh + (size_t)row * D_DIM + lane * 4) = h0;
  *(f16x4*)(znh + (size_t)row * D_DIM + 256 + lane * 4) = h1;
  if (lane == 0) { znorm[row] = m; znorm2[row] = s2; }
}

__global__ __launch_bounds__(64) void prep_cb_kernel(
    const float* __restrict__ emb, float* __restrict__ cb32,
    _Float16* __restrict__ cbh, float* __restrict__ cnorm2) {
  const int row = blockIdx.x;
  const int lane = threadIdx.x;
  const float4* xr = (const float4*)(emb + (size_t)row * D_DIM);
  float4 v0 = xr[lane];
  float4 v1 = xr[lane + 64];
  float ss = v0.x * v0.x + v0.y * v0.y + v0.z * v0.z + v0.w * v0.w
           + v1.x * v1.x + v1.y * v1.y + v1.z * v1.z + v1.w * v1.w;
#pragma unroll
  for (int s = 32; s > 0; s >>= 1) ss += __shfl_xor(ss, s, 64);
  const float m = fmaxf(sqrtf(ss), EPS_NORM);
  float4 o0, o1;
  o0.x = v0.x / m; o0.y = v0.y / m; o0.z = v0.z / m; o0.w = v0.w / m;
  o1.x = v1.x / m; o1.y = v1.y / m; o1.z = v1.z / m; o1.w = v1.w / m;
  float s2 = o0.x * o0.x + o0.y * o0.y + o0.z * o0.z + o0.w * o0.w
           + o1.x * o1.x + o1.y * o1.y + o1.z * o1.z + o1.w * o1.w;
#pragma unroll
  for (int s = 32; s > 0; s >>= 1) s2 += __shfl_xor(s2, s, 64);
  float4* co = (float4*)(cb32 + (size_t)row * D_DIM);
  co[lane] = o0;
  co[lane + 64] = o1;
  f16x4 h0, h1;
  h0[0] = (_Float16)o0.x; h0[1] = (_Float16)o0.y; h0[2] = (_Float16)o0.z; h0[3] = (_Float16)o0.w;
  h1[0] = (_Float16)o1.x; h1[1] = (_Float16)o1.y; h1[2] = (_Float16)o1.z; h1[3] = (_Float16)o1.w;
  *(f16x4*)(cbh + (size_t)row * D_DIM + lane * 4) = h0;
  *(f16x4*)(cbh + (size_t)row * D_DIM + 256 + lane * 4) = h1;
  if (lane == 0) cnorm2[row] = s2;
}

__global__ void zero_count_kernel(unsigned* __restrict__ counters) {
  if (threadIdx.x < 2) counters[threadIdx.x] = 0;
}

// ---------------------------------------------------------------------------
// Screening GEMM (unchanged from round 2): S = znh . cbh^T via
// mfma_f32_16x16x32_f16, 128x128 tile, wave-private 32x128 strips,
// global_load_lds width-16 staging. Emits per-(row, block) top-1 key
// (val|idx) in K1 and top-2 ordered value in K2.
// ---------------------------------------------------------------------------
__global__ __launch_bounds__(256) void screen_gemm_kernel(
    const _Float16* __restrict__ znh, const _Float16* __restrict__ cbh,
    u64* __restrict__ K1, unsigned* __restrict__ K2) {
  __shared__ _Float16 Ash[128 * 32];
  __shared__ _Float16 Bsh[128 * 32];
  const int tid = (int)threadIdx.x;
  const int lane = tid & 63;
  const int w = tid >> 6;
  const int m0 = blockIdx.y * 128;
  const int n0 = blockIdx.x * 128;

  f32x4 acc[2][8];
  const f32x4 z4 = {0.0f, 0.0f, 0.0f, 0.0f};
#pragma unroll
  for (int i = 0; i < 2; i++)
#pragma unroll
    for (int j = 0; j < 8; j++) acc[i][j] = z4;

  const int srow = lane >> 2;
  const int kc = (lane & 3) * 8;
  const _Float16* gA0 = znh + (size_t)(m0 + w * 32 + srow) * D_DIM + kc;
  const _Float16* gA1 = znh + (size_t)(m0 + w * 32 + 16 + srow) * D_DIM + kc;
  const _Float16* gB0 = cbh + (size_t)(n0 + w * 32 + srow) * D_DIM + kc;
  const _Float16* gB1 = cbh + (size_t)(n0 + w * 32 + 16 + srow) * D_DIM + kc;
  _Float16* lA0 = Ash + w * 1024;
  _Float16* lA1 = Ash + w * 1024 + 512;
  _Float16* lB0 = Bsh + w * 1024;
  _Float16* lB1 = Bsh + w * 1024 + 512;

  const int q = lane >> 4;
  const int c15 = lane & 15;
  const _Float16* aRd = Ash + (w * 32 + c15) * 32 + q * 8;
  const _Float16* bRd = Bsh + c15 * 32 + q * 8;

  for (int d0 = 0; d0 < D_DIM; d0 += 32) {
    __syncthreads();
    async_copy16(lA0, gA0 + d0);
    async_copy16(lA1, gA1 + d0);
    async_copy16(lB0, gB0 + d0);
    async_copy16(lB1, gB1 + d0);
    __syncthreads();
    f16x8 a0 = *(const f16x8*)(aRd);
    f16x8 a1 = *(const f16x8*)(aRd + 16 * 32);
    f16x8 bf[8];
#pragma unroll
    for (int nt = 0; nt < 8; nt++) bf[nt] = *(const f16x8*)(bRd + nt * 16 * 32);
#pragma unroll
    for (int nt = 0; nt < 8; nt++) {
      acc[0][nt] = __builtin_amdgcn_mfma_f32_16x16x32_f16(a0, bf[nt], acc[0][nt], 0, 0, 0);
      acc[1][nt] = __builtin_amdgcn_mfma_f32_16x16x32_f16(a1, bf[nt], acc[1][nt], 0, 0, 0);
    }
  }

#pragma unroll
  for (int mt = 0; mt < 2; mt++) {
#pragma unroll
    for (int r = 0; r < 4; r++) {
      u64 key1 = ~0ull;
      unsigned b2 = 0xFFFFFFFFu;
#pragma unroll
      for (int nt = 0; nt < 8; nt++) {
        unsigned ub = orderf(-acc[mt][nt][r]);
        unsigned col = (unsigned)(n0 + nt * 16 + c15);
        u64 k = ((u64)ub << 32) | (u64)col;
        unsigned v1 = (unsigned)(key1 >> 32);
        if (k < key1) { b2 = umin32(b2, v1); key1 = k; }
        else          { b2 = umin32(b2, ub); }
      }
#pragma unroll
      for (int s = 1; s <= 8; s <<= 1) {
        u64 ok = shfl_xor_u64(key1, s);
        unsigned ob2 = (unsigned)__shfl_xor((int)b2, s, 64);
        unsigned ov = (unsigned)(ok >> 32);
        unsigned v1 = (unsigned)(key1 >> 32);
        unsigned lose = (ok < key1) ? v1 : ov;
        b2 = umin32(umin32(b2, ob2), lose);
        key1 = umin64(key1, ok);
      }
      if (c15 == 0) {
        const int mrow = m0 + w * 32 + mt * 16 + q * 4 + r;
        K1[(size_t)mrow * NB + blockIdx.x] = key1;
        K2[(size_t)mrow * NB + blockIdx.x] = b2;
      }
    }
  }
}

// ---------------------------------------------------------------------------
// Certify v2: one wave per row, lane = block.
//  thr = approx_top1 + MARGIN.
//  - any block with top2 <= thr, or >CAP candidates  -> heavy list (rare)
//  - exactly 1 candidate code                        -> certified, done
//  - else                                            -> light list + compact
//                                                       candidate code array
// ---------------------------------------------------------------------------
__global__ __launch_bounds__(256) void certify_kernel(
    const u64* __restrict__ K1, const unsigned* __restrict__ K2,
    unsigned* __restrict__ idx_final, unsigned* __restrict__ candList,
    unsigned* __restrict__ candCount, unsigned* __restrict__ lightList,
    unsigned* __restrict__ heavyList, unsigned* __restrict__ counters) {
  const int row = blockIdx.x * 4 + (int)(threadIdx.x >> 6);
  const int b = (int)(threadIdx.x & 63);
  u64 k = K1[(size_t)row * NB + b];
  unsigned t2 = K2[(size_t)row * NB + b];
  u64 kmin = k;
#pragma unroll
  for (int s = 1; s <= 32; s <<= 1) kmin = umin64(kmin, shfl_xor_u64(kmin, s));
  const float t1f = unorderf((unsigned)(kmin >> 32));
  const unsigned thr = orderf(t1f + MARGIN);
  const bool cand = ((unsigned)(k >> 32)) <= thr;
  const bool heavy = (t2 <= thr);
  u64 cmask = __ballot(cand);
  u64 hmask = __ballot(heavy);
  const int nc = __popcll(cmask);
  if (hmask != 0 || nc > CAP) {
    if (b == 0) {
      unsigned p = atomicAdd(counters + 1, 1u);
      heavyList[p] = (unsigned)row;
    }
  } else if (nc == 1) {
    if (b == 0) idx_final[row] = (unsigned)(kmin & 0xFFFFFFFFull);
  } else {
    if (cand) {
      int pos = __popcll(cmask & ((b == 0) ? 0ull : (~0ull >> (64 - b))));
      candList[(size_t)row * CAP + pos] = (unsigned)(k & 0xFFFFFFFFull);
    }
    if (b == 0) {
      candCount[row] = (unsigned)nc;
      unsigned p = atomicAdd(counters + 0, 1u);
      lightList[p] = (unsigned)row;
    }
  }
}

// ---------------------------------------------------------------------------
// Light rescore: one wave per flagged row; exact fp32 dist for each candidate
// code (coalesced 2KB row reads), argmin with lowest-index tie-break.
// ---------------------------------------------------------------------------
__global__ __launch_bounds__(64) void rescore_light_kernel(
    const float* __restrict__ z, const float* __restrict__ cb32,
    const float* __restrict__ znorm, const float* __restrict__ znorm2,
    const float* __restrict__ cnorm2, const unsigned* __restrict__ candList,
    const unsigned* __restrict__ candCount,
    const unsigned* __restrict__ lightList,
    const unsigned* __restrict__ counters, unsigned* __restrict__ idx_final) {
  const int lane = (int)threadIdx.x;
  const unsigned n = counters[0];
  for (unsigned i = blockIdx.x; i < n; i += gridDim.x) {
    const int row = (int)lightList[i];
    const float m = znorm[row];
    const float zn2 = znorm2[row];
    const float4* zr = (const float4*)(z + (size_t)row * D_DIM);
    float4 v0 = zr[lane], v1 = zr[lane + 64];
    float4 o0, o1;
    o0.x = v0.x / m; o0.y = v0.y / m; o0.z = v0.z / m; o0.w = v0.w / m;
    o1.x = v1.x / m; o1.y = v1.y / m; o1.z = v1.z / m; o1.w = v1.w / m;
    const unsigned nc = candCount[row];
    u64 best = ~0ull;
    for (unsigned j = 0; j < nc; j++) {
      const unsigned c = candList[(size_t)row * CAP + j];
      const float4* qr = (const float4*)(cb32 + (size_t)c * D_DIM);
      float4 q0 = qr[lane], q1 = qr[lane + 64];
      float p = o0.x * q0.x + o0.y * q0.y + o0.z * q0.z + o0.w * q0.w
              + o1.x * q1.x + o1.y * q1.y + o1.z * q1.z + o1.w * q1.w;
#pragma unroll
      for (int s = 32; s > 0; s >>= 1) p += __shfl_xor(p, s, 64);
      float dist = __fadd_rn(__fsub_rn(zn2, __fmul_rn(2.0f, p)), cnorm2[c]);
      u64 key = ((u64)orderf(dist) << 32) | (u64)c;
      best = umin64(best, key);
    }
    if (lane == 0) idx_final[row] = (unsigned)(best & 0xFFFFFFFFull);
  }
}

// ---------------------------------------------------------------------------
// Heavy rescore (rare rows): full fp32 scan of every block whose top-1 is
// within MARGIN (superset of all candidates). Round-2 semantics.
// ---------------------------------------------------------------------------
__global__ __launch_bounds__(64) void rescore_heavy_kernel(
    const float* __restrict__ z, const float* __restrict__ cb32,
    const float* __restrict__ znorm, const float* __restrict__ znorm2,
    const float* __restrict__ cnorm2, const u64* __restrict__ K1,
    const unsigned* __restrict__ heavyList,
    const unsigned* __restrict__ counters, unsigned* __restrict__ idx_final) {
  __shared__ float znl[D_DIM];
  const int lane = (int)threadIdx.x;
  const unsigned n = counters[1];
  for (unsigned i = blockIdx.x; i < n; i += gridDim.x) {
    const int row = (int)heavyList[i];
    const float m = znorm[row];
    const float4* zr = (const float4*)(z + (size_t)row * D_DIM);
    float4 v0 = zr[lane], v1 = zr[lane + 64];
    __syncthreads();
    float4 o0, o1;
    o0.x = v0.x / m; o0.y = v0.y / m; o0.z = v0.z / m; o0.w = v0.w / m;
    o1.x = v1.x / m; o1.y = v1.y / m; o1.z = v1.z / m; o1.w = v1.w / m;
    *(float4*)&znl[lane * 4] = o0;
    *(float4*)&znl[256 + lane * 4] = o1;
    u64 k = K1[(size_t)row * NB + lane];
    u64 kmin = k;
#pragma unroll
    for (int s = 1; s <= 32; s <<= 1) kmin = umin64(kmin, shfl_xor_u64(kmin, s));
    const float t1 = unorderf((unsigned)(kmin >> 32));
    const bool cf = unorderf((unsigned)(k >> 32)) <= t1 + MARGIN;
    u64 mask = __ballot(cf);
    __syncthreads();
    const float zn2 = znorm2[row];
    u64 best = ~0ull;
    while (mask) {
      const int b = __builtin_ctzll(mask);
      mask &= mask - 1;
#pragma unroll
      for (int h = 0; h < 2; h++) {
        const int c = b * 128 + h * 64 + lane;
        const float4* cr = (const float4*)(cb32 + (size_t)c * D_DIM);
        float dot = 0.0f;
        for (int d = 0; d < 128; d++) {
          float4 bb = cr[d];
          float4 aa = *(const float4*)&znl[d * 4];
          dot = __fmaf_rn(aa.x, bb.x, dot);
          dot = __fmaf_rn(aa.y, bb.y, dot);
          dot = __fmaf_rn(aa.z, bb.z, dot);
          dot = __fmaf_rn(aa.w, bb.w, dot);
        }
        float dist = __fadd_rn(__fsub_rn(zn2, __fmul_rn(2.0f, dot)), cnorm2[c]);
        u64 key = ((u64)orderf(dist) << 32) | (u64)(unsigned)c;
        best = umin64(best, key);
      }
    }
#pragma unroll
    for (int s = 1; s <= 32; s <<= 1) best = umin64(best, shfl_xor_u64(best, s));
    if (lane == 0) idx_final[row] = (unsigned)(best & 0xFFFFFFFFull);
  }
}

// ---------------------------------------------------------------------------
// Finalize: gather code, project, write outputs. One wave per row.
// ---------------------------------------------------------------------------
__global__ __launch_bounds__(64) void finalize_kernel(
    const float* __restrict__ z, const float* __restrict__ cb32,
    const float* __restrict__ znorm, const unsigned* __restrict__ idx_final,
    float* __restrict__ out) {
  const int row = blockIdx.x;
  const int lane = (int)threadIdx.x;
  const float m = znorm[row];
  const unsigned idx = idx_final[row];
  const float4* zr = (const float4*)(z + (size_t)row * D_DIM);
  const float4* qr = (const float4*)(cb32 + (size_t)idx * D_DIM);
  float4 v0 = zr[lane], v1 = zr[lane + 64];
  float4 q0 = qr[lane], q1 = qr[lane + 64];
  float4 z0, z1;
  z0.x = v0.x / m; z0.y = v0.y / m; z0.z = v0.z / m; z0.w = v0.w / m;
  z1.x = v1.x / m; z1.y = v1.y / m; z1.z = v1.z / m; z1.w = v1.w / m;
  float p = z0.x * q0.x + z0.y * q0.y + z0.z * q0.z + z0.w * q0.w
          + z1.x * q1.x + z1.y * q1.y + z1.z * q1.z + z1.w * q1.w;
#pragma unroll
  for (int s = 32; s > 0; s >>= 1) p += __shfl_xor(p, s, 64);
  float4 o0, o1;
  o0.x = p * q0.x; o0.y = p * q0.y; o0.z = p * q0.z; o0.w = p * q0.w;
  o1.x = p * q1.x; o1.y = p * q1.y; o1.z = p * q1.z; o1.w = p * q1.w;
  float4* orow = (float4*)(out + (size_t)row * D_DIM);
  orow[lane] = o0;
  orow[lane + 64] = o1;
  if (lane == 0) out[(size_t)N_ROWS * D_DIM + row] = (float)idx;
}

// ---------------------------------------------------------------------------
extern "C" void kernel_launch(void* const* d_in, const int* in_sizes, int n_in,
                              void* d_out, int out_size, void* d_ws,
                              size_t ws_size, hipStream_t stream) {
  const float* z = (const float*)d_in[0];
  const float* emb = (const float*)d_in[1];
  float* out = (float*)d_out;

  // ws layout, ~142 MB total:
  u64* K1 = (u64*)d_ws;                                   // 32 MB
  unsigned* K2 = (unsigned*)(K1 + (size_t)N_ROWS * NB);   // 16 MB
  float* cb32 = (float*)(K2 + (size_t)N_ROWS * NB);       // 16 MB
  float* znorm = cb32 + (size_t)K_CODES * D_DIM;          // 256 KB
  float* znorm2 = znorm + N_ROWS;                         // 256 KB
  float* cnorm2 = znorm2 + N_ROWS;                        // 32 KB
  unsigned* idx_final = (unsigned*)(cnorm2 + K_CODES);    // 256 KB
  unsigned* lightList = idx_final + N_ROWS;               // 256 KB
  unsigned* heavyList = lightList + N_ROWS;               // 256 KB
  unsigned* candCount = heavyList + N_ROWS;               // 256 KB
  unsigned* counters = candCount + N_ROWS;                // 64*4 pad
  unsigned* candList = counters + 64;                     // 4 MB
  _Float16* znh = (_Float16*)(candList + (size_t)N_ROWS * CAP);  // 64 MB
  _Float16* cbh = znh + (size_t)N_ROWS * D_DIM;           // 8 MB

  prep_z_kernel<<<N_ROWS, 64, 0, stream>>>(z, znh, znorm, znorm2);
  prep_cb_kernel<<<K_CODES, 64, 0, stream>>>(emb, cb32, cbh, cnorm2);
  zero_count_kernel<<<1, 64, 0, stream>>>(counters);

  dim3 grid(K_CODES / 128, N_ROWS / 128);
  screen_gemm_kernel<<<grid, 256, 0, stream>>>(znh, cbh, K1, K2);

  certify_kernel<<<N_ROWS / 4, 256, 0, stream>>>(
      K1, K2, idx_final, candList, candCount, lightList, heavyList, counters);
  rescore_light_kernel<<<8192, 64, 0, stream>>>(
      z, cb32, znorm, znorm2, cnorm2, candList, candCount, lightList, counters,
      idx_final);
  rescore_heavy_kernel<<<512, 64, 0, stream>>>(
      z, cb32, znorm, znorm2, cnorm2, K1, heavyList, counters, idx_final);
  finalize_kernel<<<N_ROWS, 64, 0, stream>>>(z, cb32, znorm, idx_final, out);
}